// Round 10
// baseline (65.708 us; speedup 1.0000x reference)
//
#include <hip/hip_runtime.h>
#include <hip/hip_bf16.h>
#include <hip/hip_fp16.h>

// Problem constants (B=4, C=256, H=W=64, hs=ws=32, rate=2, vk=4, pad=1)
#define BB 4
#define CC 256
#define HH 64
#define WW 64
#define QRN 1024
#define KN  1024
#define NN  4096
#define KDIM 1120            // 33*33 = 1089 padded to 35*32
#define MROWS 1024           // pixels per parity class

typedef _Float16 f16x8 __attribute__((ext_vector_type(8)));
typedef float f32x4 __attribute__((ext_vector_type(4)));
typedef float f32x16 __attribute__((ext_vector_type(16)));

#define AP_ELEMS ((size_t)16 * MROWS * KDIM)   // 18,350,080 halves
#define BP_ELEMS ((size_t)16 * CC * KDIM)      //  4,587,520 halves

// ===========================================================================
// FAST PATH
// ===========================================================================

// Combined scores, DEDUPED: v(b,Qa,Ra,k) is identical for all 4 parity
// classes; compute once (4 masked loads) and scatter to <=4 class slots.
//   v = sum_{dq,dr} [masks] s[b][(Qa-dq)*32+(Ra-dr)][(mp-dq)*32+(np-dr)]
//   Ap[b*4+ph*2+pw][(Qa-ph)*32+(Ra-pw)][k] = v   (when Qa-ph,Ra-pw valid)
// grid (5, 1089, 4): x = k-chunk, y = Qa*33+Ra, z = b.
__global__ __launch_bounds__(256)
void build_A(const float* __restrict__ s, _Float16* __restrict__ Ap) {
    int k = blockIdx.x * 256 + threadIdx.x;
    if (k >= KDIM) return;
    int qr = blockIdx.y;                    // Qa*33 + Ra
    int Qa = (qr * 993) >> 15;              // qr/33, exact for qr < 2048
    int Ra = qr - 33 * Qa;
    int b  = blockIdx.z;

    int mp = (k * 993) >> 15;               // k/33 (exact for k < 2048)
    int np = k - 33 * mp;
    const bool q0 = (Qa < 32), q1 = (Qa >= 1);         // block-uniform
    const bool r0 = (Ra < 32), r1 = (Ra >= 1);         // block-uniform
    const bool m0 = (mp < 32), m1 = (mp >= 1) && (mp < 33);
    const bool n0 = (np < 32), n1 = (np >= 1);
    const int col = (mp << 5) + np;
    const float* sb = s + (size_t)b * QRN * KN;

    float v = 0.f;
    if (q0 & r0 & m0 & n0) v += sb[(size_t)((Qa << 5) + Ra) * KN + col];
    if (q0 & r1 & m0 & n1) v += sb[(size_t)((Qa << 5) + Ra - 1) * KN + col - 1];
    if (q1 & r0 & m1 & n0) v += sb[(size_t)(((Qa - 1) << 5) + Ra) * KN + col - 32];
    if (q1 & r1 & m1 & n1) v += sb[(size_t)(((Qa - 1) << 5) + Ra - 1) * KN + col - 33];

    const _Float16 hv = (_Float16)v;
    // scatter to the valid classes (conditions are block-uniform)
    if (q0 & r0)
        Ap[((size_t)(b * 4 + 0) * MROWS + (Qa << 5) + Ra) * KDIM + k] = hv;
    if (q0 & r1)
        Ap[((size_t)(b * 4 + 1) * MROWS + (Qa << 5) + Ra - 1) * KDIM + k] = hv;
    if (q1 & r0)
        Ap[((size_t)(b * 4 + 2) * MROWS + ((Qa - 1) << 5) + Ra) * KDIM + k] = hv;
    if (q1 & r1)
        Ap[((size_t)(b * 4 + 3) * MROWS + ((Qa - 1) << 5) + Ra - 1) * KDIM + k] = hv;
}

// Gathered x samples. Thread = one k, loops 32 channels (same gather
// coordinates, different planes).
// Bp[bc][c][k] = x[b][c][clamp(2m'+ua-1)][clamp(2n'+va-1)], ua=1-ph, va=1-pw
// grid (5, 16, 8): x=k-chunk, y=bc, z=c-group.
__global__ __launch_bounds__(256)
void build_B(const float* __restrict__ x, _Float16* __restrict__ Bp) {
    int k = blockIdx.x * 256 + threadIdx.x;
    if (k >= KDIM) return;
    int bc = blockIdx.y;
    int cg = blockIdx.z;
    int b = bc >> 2, cls = bc & 3;
    int ph = cls >> 1, pw = cls & 1;
    int ua = 1 - ph, va = 1 - pw;

    int mp = (k * 993) >> 15;
    int np = k - 33 * mp;
    int rr = 2 * mp + ua - 1; rr = min(max(rr, 0), HH - 1);
    int cc2 = 2 * np + va - 1; cc2 = min(max(cc2, 0), WW - 1);
    const int off = rr * WW + cc2;

    const float* xb = x + ((size_t)b * CC + cg * 32) * HH * WW;
    _Float16* bpb = Bp + ((size_t)bc * CC + cg * 32) * KDIM + k;

    #pragma unroll 8
    for (int i = 0; i < 32; ++i) {
        bpb[(size_t)i * KDIM] = (_Float16)xb[(size_t)i * HH * WW + off];
    }
}

// GEMM per (b,class): D[c][px] = sum_k Bp[c][k] * Ap[px][k]
// Tile 64(c) x 128(px), 512 blocks (2/CU), 4 waves (2x2 of 32x64),
// K-step 32, mfma_f32_32x32x16_f16.
// PF=4 register prefetch ring (statically indexed via full unroll),
// double-buffered LDS, raw s_barrier + lgkmcnt(0) (loads stay in flight
// across barriers — no vmcnt(0) drain).
// Epilogue: out = ori_x + 0.25*alpha*D  (each output pixel exactly once).
#define A_SLOT 520       // 64*8 + 8 halves
#define B_SLOT 1040      // 128*8 + 8 halves
#define PF 4
#define NT 35            // KDIM/32
__global__ __launch_bounds__(256)
void gemm_f16(const _Float16* __restrict__ Ap,   // [16][1024][1120] (px side)
              const _Float16* __restrict__ Bp,   // [16][256][1120]  (c side)
              const float* __restrict__ orix,
              const float* __restrict__ alphap,
              float* __restrict__ out) {
    __shared__ __align__(16) _Float16 Am[2][4 * A_SLOT];   // channel tile
    __shared__ __align__(16) _Float16 Bn[2][4 * B_SLOT];   // pixel tile

    // XCD-grouping remap: consecutive dispatch ids round-robin XCDs; give
    // each residue class one contiguous chunk of work (2 bc panels).
    const int lin = blockIdx.x + 4 * (blockIdx.y + 8 * blockIdx.z); // 0..511
    const int wid = (lin & 7) * 64 + (lin >> 3);
    const int bc  = wid >> 5;
    const int byy = (wid >> 2) & 7;
    const int bxx = wid & 3;

    const int b = bc >> 2, cls = bc & 3;
    const int ph = cls >> 1, pw = cls & 1;
    const int c0  = bxx * 64;
    const int px0 = byy * 128;

    const int t = threadIdx.x;
    const int wv = t >> 6, l = t & 63;
    const int lr = l & 31;                // row within 32-tile
    const int lh = l >> 5;                // k-half selector
    const int wr = wv >> 1, wc = wv & 1;  // wave grid: 2(m of 32) x 2(n of 64)

    const _Float16* Ag = Bp + ((size_t)bc * CC + c0) * KDIM;     // M operand
    const _Float16* Bg = Ap + ((size_t)bc * MROWS + px0) * KDIM; // N operand

    const int st_row  = t >> 2;           // 0..63
    const int st_slot = t & 3;

    f32x16 acc[2];
    acc[0] = (f32x16)(0.f);
    acc[1] = (f32x16)(0.f);

    f16x8 rga[PF], rgb0[PF], rgb1[PF];

    // ---- prologue: issue loads for steps 0..PF-1
    #pragma unroll
    for (int s2 = 0; s2 < PF; ++s2) {
        const size_t kb = s2 * 32 + st_slot * 8;
        rga[s2]  = *reinterpret_cast<const f16x8*>(Ag + (size_t)st_row * KDIM + kb);
        rgb0[s2] = *reinterpret_cast<const f16x8*>(Bg + (size_t)st_row * KDIM + kb);
        rgb1[s2] = *reinterpret_cast<const f16x8*>(Bg + (size_t)(st_row + 64) * KDIM + kb);
    }
    // write step 0 into buf 0
    *reinterpret_cast<f16x8*>(&Am[0][st_slot * A_SLOT + st_row * 8]) = rga[0];
    *reinterpret_cast<f16x8*>(&Bn[0][st_slot * B_SLOT + st_row * 8]) = rgb0[0];
    *reinterpret_cast<f16x8*>(&Bn[0][st_slot * B_SLOT + (st_row + 64) * 8]) = rgb1[0];
    asm volatile("s_waitcnt lgkmcnt(0)" ::: "memory");
    __builtin_amdgcn_s_barrier();

    #pragma unroll
    for (int ts = 0; ts < NT; ++ts) {
        const int cur = ts & 1;
        // issue prefetch for step ts+PF into the slot just freed
        if (ts + PF < NT) {
            const int sl = ts & 3;        // == (ts+PF) & 3
            const size_t kb = (size_t)(ts + PF) * 32 + st_slot * 8;
            rga[sl]  = *reinterpret_cast<const f16x8*>(Ag + (size_t)st_row * KDIM + kb);
            rgb0[sl] = *reinterpret_cast<const f16x8*>(Bg + (size_t)st_row * KDIM + kb);
            rgb1[sl] = *reinterpret_cast<const f16x8*>(Bg + (size_t)(st_row + 64) * KDIM + kb);
        }

        // compute on buf[cur]
        f16x8 af[2], bf[2][2];
        #pragma unroll
        for (int kk = 0; kk < 2; ++kk)
            af[kk] = *reinterpret_cast<const f16x8*>(
                &Am[cur][(kk * 2 + lh) * A_SLOT + (wr * 32 + lr) * 8]);
        #pragma unroll
        for (int nt2 = 0; nt2 < 2; ++nt2)
            #pragma unroll
            for (int kk = 0; kk < 2; ++kk)
                bf[nt2][kk] = *reinterpret_cast<const f16x8*>(
                    &Bn[cur][(kk * 2 + lh) * B_SLOT +
                             (wc * 64 + nt2 * 32 + lr) * 8]);
        #pragma unroll
        for (int kk = 0; kk < 2; ++kk)
            #pragma unroll
            for (int nt2 = 0; nt2 < 2; ++nt2)
                acc[nt2] = __builtin_amdgcn_mfma_f32_32x32x16_f16(
                    af[kk], bf[nt2][kk], acc[nt2], 0, 0, 0);

        // write step ts+1 into the other buffer (regs already in flight;
        // compiler inserts the precise vmcnt for these registers)
        if (ts + 1 < NT) {
            const int ns = (ts + 1) & 3, nb = cur ^ 1;
            *reinterpret_cast<f16x8*>(&Am[nb][st_slot * A_SLOT + st_row * 8]) = rga[ns];
            *reinterpret_cast<f16x8*>(&Bn[nb][st_slot * B_SLOT + st_row * 8]) = rgb0[ns];
            *reinterpret_cast<f16x8*>(&Bn[nb][st_slot * B_SLOT + (st_row + 64) * 8]) = rgb1[ns];
        }
        asm volatile("s_waitcnt lgkmcnt(0)" ::: "memory");
        __builtin_amdgcn_s_barrier();
    }

    // epilogue: D row (M=c) = (r&3)+8*(r>>2)+4*lh; D col (N=px) = lr
    const float scale = 0.25f * alphap[0];
    #pragma unroll
    for (int nt2 = 0; nt2 < 2; ++nt2) {
        #pragma unroll
        for (int r = 0; r < 16; ++r) {
            int c  = c0 + wr * 32 + (r & 3) + 8 * (r >> 2) + 4 * lh;
            int px = px0 + wc * 64 + nt2 * 32 + lr;
            int hh = px >> 5, ww2 = px & 31;
            int h = 2 * hh + ph, wp = 2 * ww2 + pw;
            size_t idx = (((size_t)b * CC + c) * HH + h) * WW + wp;
            out[idx] = orix[idx] + scale * acc[nt2][r];
        }
    }
}

// ===========================================================================
// FALLBACK PATH (round-1 kernels, used only if ws too small)
// ===========================================================================
#define TILE_M 64
#define TILE_N 64
#define TILE_K 16

__global__ void copy_kernel(const float* __restrict__ src,
                            float* __restrict__ dst, int n4) {
    int i = blockIdx.x * blockDim.x + threadIdx.x;
    if (i < n4)
        reinterpret_cast<float4*>(dst)[i] =
            reinterpret_cast<const float4*>(src)[i];
}

__global__ void transpose_kernel(const float* __restrict__ x,
                                 float* __restrict__ xT) {
    __shared__ float tile[32][33];
    int bh = blockIdx.z;
    int b = bh >> 6, h = bh & 63;
    int c0 = blockIdx.y * 32, w0 = blockIdx.x * 32;
    int tw = threadIdx.x & 31;
    int tc = threadIdx.x >> 5;
    #pragma unroll
    for (int i = 0; i < 4; ++i) {
        int c = tc + i * 8;
        tile[c][tw] = x[(((size_t)b * CC + c0 + c) * HH + h) * WW + w0 + tw];
    }
    __syncthreads();
    int tcw = threadIdx.x & 31;
    int twr = threadIdx.x >> 5;
    #pragma unroll
    for (int i = 0; i < 4; ++i) {
        int w = twr + i * 8;
        xT[(((size_t)b * HH + h) * WW + w0 + w) * CC + c0 + tcw] = tile[tcw][w];
    }
}

__global__ __launch_bounds__(256)
void pgemm_scatter(const float* __restrict__ scores,
                   const float* __restrict__ xT,
                   const float* __restrict__ x,
                   const float* __restrict__ alpha,
                   float* __restrict__ out,
                   int use_xt) {
    __shared__ float As[TILE_K][TILE_M];
    __shared__ float Bs[TILE_K][TILE_N];

    const int b      = blockIdx.z;
    const int tile_n = blockIdx.x;
    const int m0     = blockIdx.y * TILE_M;
    const int uv     = tile_n >> 2;
    const int u      = uv >> 2, v = uv & 3;
    const int c0     = (tile_n & 3) * 64;

    const int t  = threadIdx.x;
    const int tx = t & 15;
    const int ty = t >> 4;

    float acc[4][4] = {};
    const float* sb = scores + (size_t)b * QRN * KN;

    for (int k0 = 0; k0 < KN; k0 += TILE_K) {
        {
            int mr = t >> 2;
            int kc = (t & 3) * 4;
            float4 av = *reinterpret_cast<const float4*>(
                sb + (size_t)(m0 + mr) * KN + k0 + kc);
            As[kc + 0][mr] = av.x;
            As[kc + 1][mr] = av.y;
            As[kc + 2][mr] = av.z;
            As[kc + 3][mr] = av.w;
        }
        {
            int kr = t >> 4;
            int kg = k0 + kr;
            int m  = kg >> 5, n = kg & 31;
            int rr = 2 * m + u - 1; rr = min(max(rr, 0), HH - 1);
            int cc = 2 * n + v - 1; cc = min(max(cc, 0), WW - 1);
            int ccol = (t & 15) * 4;
            if (use_xt) {
                float4 bv = *reinterpret_cast<const float4*>(
                    xT + ((((size_t)b * HH + rr) * WW + cc) * CC) + c0 + ccol);
                Bs[kr][ccol + 0] = bv.x;
                Bs[kr][ccol + 1] = bv.y;
                Bs[kr][ccol + 2] = bv.z;
                Bs[kr][ccol + 3] = bv.w;
            } else {
                #pragma unroll
                for (int j = 0; j < 4; ++j) {
                    int c = c0 + ccol + j;
                    Bs[kr][ccol + j] =
                        x[(((size_t)b * CC + c) * HH + rr) * WW + cc];
                }
            }
        }
        __syncthreads();

        #pragma unroll
        for (int k = 0; k < TILE_K; ++k) {
            float a4[4], b4[4];
            *reinterpret_cast<float4*>(a4) =
                *reinterpret_cast<const float4*>(&As[k][ty * 4]);
            *reinterpret_cast<float4*>(b4) =
                *reinterpret_cast<const float4*>(&Bs[k][tx * 4]);
            #pragma unroll
            for (int i = 0; i < 4; ++i)
                #pragma unroll
                for (int j = 0; j < 4; ++j)
                    acc[i][j] += a4[i] * b4[j];
        }
        __syncthreads();
    }

    const float scale = alpha[0] * 0.25f;
    #pragma unroll
    for (int i = 0; i < 4; ++i) {
        int qr = m0 + ty * 4 + i;
        int Q = qr >> 5, R = qr & 31;
        int h = 2 * Q + u - 1;
        int w = 2 * R + v - 1;
        if (h < 0 || h >= HH || w < 0 || w >= WW) continue;
        #pragma unroll
        for (int j = 0; j < 4; ++j) {
            int c = c0 + tx * 4 + j;
            atomicAdd(&out[(((size_t)b * CC + c) * HH + h) * WW + w],
                      acc[i][j] * scale);
        }
    }
}

// ===========================================================================
extern "C" void kernel_launch(void* const* d_in, const int* in_sizes, int n_in,
                              void* d_out, int out_size, void* d_ws,
                              size_t ws_size, hipStream_t stream) {
    const float* ori_x  = (const float*)d_in[0];
    const float* scores = (const float*)d_in[1];
    const float* alpha  = (const float*)d_in[2];
    float* out = (float*)d_out;

    const size_t need_fast = (AP_ELEMS + BP_ELEMS) * sizeof(_Float16);

    if (ws_size >= need_fast) {
        _Float16* Ap = (_Float16*)d_ws;
        _Float16* Bp = Ap + AP_ELEMS;

        build_A<<<dim3(5, 1089, 4), 256, 0, stream>>>(scores, Ap);
        build_B<<<dim3(5, 16, 8), 256, 0, stream>>>(ori_x, Bp);
        gemm_f16<<<dim3(4, 8, 16), 256, 0, stream>>>(Ap, Bp, ori_x, alpha, out);
    } else {
        float* xT = (float*)d_ws;
        const size_t xt_bytes = (size_t)BB * HH * WW * CC * sizeof(float);
        const int use_xt = (ws_size >= xt_bytes) ? 1 : 0;

        copy_kernel<<<(BB * CC * HH * WW / 4 + 255) / 256, 256, 0, stream>>>(
            ori_x, out, BB * CC * HH * WW / 4);
        if (use_xt)
            transpose_kernel<<<dim3(WW / 32, CC / 32, BB * HH), 256, 0,
                               stream>>>(ori_x, xT);
        pgemm_scatter<<<dim3(NN / TILE_N, QRN / TILE_M, BB), 256, 0, stream>>>(
            scores, xT, ori_x, alpha, out, use_xt);
    }
}

// Round 11
// 58.896 us; speedup vs baseline: 1.1157x; 1.1157x over previous
//
#include <hip/hip_runtime.h>
#include <hip/hip_bf16.h>
#include <hip/hip_fp16.h>

// Problem constants (B=4, C=256, H=W=64, hs=ws=32, rate=2, vk=4, pad=1)
#define BB 4
#define CC 256
#define HH 64
#define WW 64
#define QRN 1024
#define KN  1024
#define NN  4096
#define KDIM 1120            // 33*33 = 1089 padded to 35*32
#define MROWS 1024           // pixels per parity class
#define TROWS 1089           // 33*33 combined-score rows per b

typedef _Float16 f16x8 __attribute__((ext_vector_type(8)));
typedef float f32x4 __attribute__((ext_vector_type(4)));
typedef float f32x16 __attribute__((ext_vector_type(16)));

#define TP_ELEMS ((size_t)BB * TROWS * KDIM)   // 4,878,720 halves (9.76 MB)
#define BP_ELEMS ((size_t)16 * CC * KDIM)      // 4,587,520 halves (9.18 MB)

// ===========================================================================
// FAST PATH
// ===========================================================================

// Combined scores, deduped AND stored once per (b,Qa,Ra,k):
//   T[b][Qa*33+Ra][k=(mp,np)] =
//     sum_{dq,dr in {0,1}} [masks] s[b][(Qa-dq)*32+(Ra-dr)][(mp-dq)*32+(np-dr)]
// All 4 parity classes read this same tensor at shifted (Qa,Ra) = (hh+ph,ww+pw).
// grid (5, 1089, 4): x = k-chunk, y = Qa*33+Ra, z = b.
__global__ __launch_bounds__(256)
void build_T(const float* __restrict__ s, _Float16* __restrict__ T) {
    int k = blockIdx.x * 256 + threadIdx.x;
    if (k >= KDIM) return;
    int qr = blockIdx.y;                    // Qa*33 + Ra
    int Qa = (qr * 993) >> 15;              // qr/33, exact for qr < 2048
    int Ra = qr - 33 * Qa;
    int b  = blockIdx.z;

    int mp = (k * 993) >> 15;               // k/33 (exact for k < 2048)
    int np = k - 33 * mp;
    const bool q0 = (Qa < 32), q1 = (Qa >= 1);         // block-uniform
    const bool r0 = (Ra < 32), r1 = (Ra >= 1);         // block-uniform
    const bool m0 = (mp < 32), m1 = (mp >= 1) && (mp < 33);
    const bool n0 = (np < 32), n1 = (np >= 1);
    const int col = (mp << 5) + np;
    const float* sb = s + (size_t)b * QRN * KN;

    float v = 0.f;
    if (q0 & r0 & m0 & n0) v += sb[(size_t)((Qa << 5) + Ra) * KN + col];
    if (q0 & r1 & m0 & n1) v += sb[(size_t)((Qa << 5) + Ra - 1) * KN + col - 1];
    if (q1 & r0 & m1 & n0) v += sb[(size_t)(((Qa - 1) << 5) + Ra) * KN + col - 32];
    if (q1 & r1 & m1 & n1) v += sb[(size_t)(((Qa - 1) << 5) + Ra - 1) * KN + col - 33];

    T[((size_t)b * TROWS + qr) * KDIM + k] = (_Float16)v;
}

// Gathered x samples (parity-disjoint per class -> no dedup possible).
// Bp[bc][c][k] = x[b][c][clamp(2mp+ua-1)][clamp(2np+va-1)], ua=1-ph, va=1-pw
// grid (5, 16, 8): x=k-chunk, y=bc, z=c-group.
__global__ __launch_bounds__(256)
void build_B(const float* __restrict__ x, _Float16* __restrict__ Bp) {
    int k = blockIdx.x * 256 + threadIdx.x;
    if (k >= KDIM) return;
    int bc = blockIdx.y;
    int cg = blockIdx.z;
    int b = bc >> 2, cls = bc & 3;
    int ph = cls >> 1, pw = cls & 1;
    int ua = 1 - ph, va = 1 - pw;

    int mp = (k * 993) >> 15;
    int np = k - 33 * mp;
    int rr = 2 * mp + ua - 1; rr = min(max(rr, 0), HH - 1);
    int cc2 = 2 * np + va - 1; cc2 = min(max(cc2, 0), WW - 1);
    const int off = rr * WW + cc2;

    const float* xb = x + ((size_t)b * CC + cg * 32) * HH * WW;
    _Float16* bpb = Bp + ((size_t)bc * CC + cg * 32) * KDIM + k;

    #pragma unroll 8
    for (int i = 0; i < 32; ++i) {
        bpb[(size_t)i * KDIM] = (_Float16)xb[(size_t)i * HH * WW + off];
    }
}

// GEMM per (b,class): D[c][px] = sum_k Bp[c][k] * T[b][trow(px,cls)][k]
// Tile 64(c) x 128(px), 512 blocks (2/CU). 4 waves = 2(n-half) x 2(k-slice):
// each wave 64m x 64n x K16 per step -> 4 ds_read_b128 per 4 MFMA (1.0 ratio).
// K-step 32, mfma_f32_32x32x16_f16, PF=4 register prefetch ring, double-
// buffered LDS, raw s_barrier + lgkmcnt(0) (prefetch stays in flight).
// After K-loop: k-slices reduced across wave pairs via LDS, epilogue by the
// ks=0 waves: out = ori_x + 0.25*alpha*D (each output pixel exactly once).
#define A_SLOT 520       // 64*8 + 8 halves
#define B_SLOT 1040      // 128*8 + 8 halves
#define PF 4
#define NT 35            // KDIM/32
#define STAGE_HALVES (2 * 4 * (A_SLOT + B_SLOT))    // 12480 halves = 24960 B
__global__ __launch_bounds__(256)
void gemm_f16(const _Float16* __restrict__ T,    // [4][1089][1120] (px side)
              const _Float16* __restrict__ Bp,   // [16][256][1120] (c side)
              const float* __restrict__ orix,
              const float* __restrict__ alphap,
              float* __restrict__ out) {
    __shared__ __align__(16) char smem[32768];   // max(stage 24960, ex 32768)
    _Float16* AmB = (_Float16*)smem;             // [2][4*A_SLOT]
    _Float16* BnB = AmB + 2 * 4 * A_SLOT;        // [2][4*B_SLOT]
    float*    ex  = (float*)smem;                // k-reduction overlay

    // XCD-grouping remap: XCD r gets 64 consecutive wids = 2 bc panels
    // (same b per XCD pair) -> T[b] (2.44MB) and Bp[bc] stay L2-resident.
    const int lin = blockIdx.x + 4 * (blockIdx.y + 8 * blockIdx.z); // 0..511
    const int wid = (lin & 7) * 64 + (lin >> 3);
    const int bc  = wid >> 5;
    const int byy = (wid >> 2) & 7;
    const int bxx = wid & 3;

    const int b = bc >> 2, cls = bc & 3;
    const int ph = cls >> 1, pw = cls & 1;
    const int c0  = bxx * 64;
    const int px0 = byy * 128;

    const int t = threadIdx.x;
    const int wv = t >> 6, l = t & 63;
    const int lr = l & 31;                // row within 32-tile
    const int lh = l >> 5;                // k-half selector
    const int wc = wv & 1;                // n-half (which 64 of 128 px)
    const int ks = wv >> 1;               // k-slice (which 16 of K-step 32)

    const _Float16* Ag = Bp + ((size_t)bc * CC + c0) * KDIM;   // M operand
    const _Float16* Tg = T + (size_t)b * TROWS * KDIM;         // N operand

    // staging: thread covers A row st_row and T rows trow0/trow1
    const int st_row  = t >> 2;           // 0..63
    const int st_slot = t & 3;
    const int pxa = px0 + st_row, pxb = px0 + st_row + 64;
    const int trow0 = ((pxa >> 5) + ph) * 33 + (pxa & 31) + pw;
    const int trow1 = ((pxb >> 5) + ph) * 33 + (pxb & 31) + pw;

    f32x16 acc[2][2];
    #pragma unroll
    for (int i = 0; i < 2; ++i)
        #pragma unroll
        for (int j = 0; j < 2; ++j)
            acc[i][j] = (f32x16)(0.f);

    f16x8 rga[PF], rgb0[PF], rgb1[PF];

    // ---- prologue: issue loads for steps 0..PF-1
    #pragma unroll
    for (int s2 = 0; s2 < PF; ++s2) {
        const size_t kb = s2 * 32 + st_slot * 8;
        rga[s2]  = *reinterpret_cast<const f16x8*>(Ag + (size_t)st_row * KDIM + kb);
        rgb0[s2] = *reinterpret_cast<const f16x8*>(Tg + (size_t)trow0 * KDIM + kb);
        rgb1[s2] = *reinterpret_cast<const f16x8*>(Tg + (size_t)trow1 * KDIM + kb);
    }
    // write step 0 into buf 0
    *reinterpret_cast<f16x8*>(&AmB[st_slot * A_SLOT + st_row * 8]) = rga[0];
    *reinterpret_cast<f16x8*>(&BnB[st_slot * B_SLOT + st_row * 8]) = rgb0[0];
    *reinterpret_cast<f16x8*>(&BnB[st_slot * B_SLOT + (st_row + 64) * 8]) = rgb1[0];
    asm volatile("s_waitcnt lgkmcnt(0)" ::: "memory");
    __builtin_amdgcn_s_barrier();

    #pragma unroll
    for (int ts = 0; ts < NT; ++ts) {
        const int cur = ts & 1;
        // issue prefetch for step ts+PF into the ring slot just freed
        if (ts + PF < NT) {
            const int sl = ts & 3;        // == (ts+PF) & 3
            const size_t kb = (size_t)(ts + PF) * 32 + st_slot * 8;
            rga[sl]  = *reinterpret_cast<const f16x8*>(Ag + (size_t)st_row * KDIM + kb);
            rgb0[sl] = *reinterpret_cast<const f16x8*>(Tg + (size_t)trow0 * KDIM + kb);
            rgb1[sl] = *reinterpret_cast<const f16x8*>(Tg + (size_t)trow1 * KDIM + kb);
        }

        // compute on buf[cur]: this wave's k-slice is slot (ks*2 + lh)
        const int slot = ks * 2 + lh;
        f16x8 af[2], bf[2];
        #pragma unroll
        for (int mt = 0; mt < 2; ++mt)
            af[mt] = *reinterpret_cast<const f16x8*>(
                &AmB[cur * 4 * A_SLOT + slot * A_SLOT + (mt * 32 + lr) * 8]);
        #pragma unroll
        for (int nt2 = 0; nt2 < 2; ++nt2)
            bf[nt2] = *reinterpret_cast<const f16x8*>(
                &BnB[cur * 4 * B_SLOT + slot * B_SLOT +
                     (wc * 64 + nt2 * 32 + lr) * 8]);
        #pragma unroll
        for (int mt = 0; mt < 2; ++mt)
            #pragma unroll
            for (int nt2 = 0; nt2 < 2; ++nt2)
                acc[mt][nt2] = __builtin_amdgcn_mfma_f32_32x32x16_f16(
                    af[mt], bf[nt2], acc[mt][nt2], 0, 0, 0);

        // write step ts+1 into the other buffer (compiler inserts the
        // precise vmcnt for these ring registers; never drains to 0)
        if (ts + 1 < NT) {
            const int ns = (ts + 1) & 3, nb = cur ^ 1;
            *reinterpret_cast<f16x8*>(&AmB[nb * 4 * A_SLOT + st_slot * A_SLOT + st_row * 8]) = rga[ns];
            *reinterpret_cast<f16x8*>(&BnB[nb * 4 * B_SLOT + st_slot * B_SLOT + st_row * 8]) = rgb0[ns];
            *reinterpret_cast<f16x8*>(&BnB[nb * 4 * B_SLOT + st_slot * B_SLOT + (st_row + 64) * 8]) = rgb1[ns];
        }
        asm volatile("s_waitcnt lgkmcnt(0)" ::: "memory");
        __builtin_amdgcn_s_barrier();
    }

    // ---- cross-wave k-slice reduction: ks=1 waves dump, ks=0 waves add.
    // Layout ex[v=mt*2+nt][wc][r][lane]: lanes consecutive -> conflict-free.
    if (ks == 1) {
        #pragma unroll
        for (int mt = 0; mt < 2; ++mt)
            #pragma unroll
            for (int nt2 = 0; nt2 < 2; ++nt2)
                #pragma unroll
                for (int r = 0; r < 16; ++r)
                    ex[((((mt * 2 + nt2) * 2 + wc) * 16) + r) * 64 + l] =
                        acc[mt][nt2][r];
    }
    asm volatile("s_waitcnt lgkmcnt(0)" ::: "memory");
    __builtin_amdgcn_s_barrier();

    if (ks == 0) {
        const float scale = 0.25f * alphap[0];
        #pragma unroll
        for (int mt = 0; mt < 2; ++mt) {
            #pragma unroll
            for (int nt2 = 0; nt2 < 2; ++nt2) {
                #pragma unroll
                for (int r = 0; r < 16; ++r) {
                    float vsum = acc[mt][nt2][r] +
                        ex[((((mt * 2 + nt2) * 2 + wc) * 16) + r) * 64 + l];
                    int c  = c0 + mt * 32 + (r & 3) + 8 * (r >> 2) + 4 * lh;
                    int px = px0 + wc * 64 + nt2 * 32 + lr;
                    int hh = px >> 5, ww2 = px & 31;
                    int h = 2 * hh + ph, wp = 2 * ww2 + pw;
                    size_t idx = (((size_t)b * CC + c) * HH + h) * WW + wp;
                    out[idx] = orix[idx] + scale * vsum;
                }
            }
        }
    }
}

// ===========================================================================
// FALLBACK PATH (round-1 kernels, used only if ws too small)
// ===========================================================================
#define TILE_M 64
#define TILE_N 64
#define TILE_K 16

__global__ void copy_kernel(const float* __restrict__ src,
                            float* __restrict__ dst, int n4) {
    int i = blockIdx.x * blockDim.x + threadIdx.x;
    if (i < n4)
        reinterpret_cast<float4*>(dst)[i] =
            reinterpret_cast<const float4*>(src)[i];
}

__global__ void transpose_kernel(const float* __restrict__ x,
                                 float* __restrict__ xT) {
    __shared__ float tile[32][33];
    int bh = blockIdx.z;
    int b = bh >> 6, h = bh & 63;
    int c0 = blockIdx.y * 32, w0 = blockIdx.x * 32;
    int tw = threadIdx.x & 31;
    int tc = threadIdx.x >> 5;
    #pragma unroll
    for (int i = 0; i < 4; ++i) {
        int c = tc + i * 8;
        tile[c][tw] = x[(((size_t)b * CC + c0 + c) * HH + h) * WW + w0 + tw];
    }
    __syncthreads();
    int tcw = threadIdx.x & 31;
    int twr = threadIdx.x >> 5;
    #pragma unroll
    for (int i = 0; i < 4; ++i) {
        int w = twr + i * 8;
        xT[(((size_t)b * HH + h) * WW + w0 + w) * CC + c0 + tcw] = tile[tcw][w];
    }
}

__global__ __launch_bounds__(256)
void pgemm_scatter(const float* __restrict__ scores,
                   const float* __restrict__ xT,
                   const float* __restrict__ x,
                   const float* __restrict__ alpha,
                   float* __restrict__ out,
                   int use_xt) {
    __shared__ float As[TILE_K][TILE_M];
    __shared__ float Bs[TILE_K][TILE_N];

    const int b      = blockIdx.z;
    const int tile_n = blockIdx.x;
    const int m0     = blockIdx.y * TILE_M;
    const int uv     = tile_n >> 2;
    const int u      = uv >> 2, v = uv & 3;
    const int c0     = (tile_n & 3) * 64;

    const int t  = threadIdx.x;
    const int tx = t & 15;
    const int ty = t >> 4;

    float acc[4][4] = {};
    const float* sb = scores + (size_t)b * QRN * KN;

    for (int k0 = 0; k0 < KN; k0 += TILE_K) {
        {
            int mr = t >> 2;
            int kc = (t & 3) * 4;
            float4 av = *reinterpret_cast<const float4*>(
                sb + (size_t)(m0 + mr) * KN + k0 + kc);
            As[kc + 0][mr] = av.x;
            As[kc + 1][mr] = av.y;
            As[kc + 2][mr] = av.z;
            As[kc + 3][mr] = av.w;
        }
        {
            int kr = t >> 4;
            int kg = k0 + kr;
            int m  = kg >> 5, n = kg & 31;
            int rr = 2 * m + u - 1; rr = min(max(rr, 0), HH - 1);
            int cc = 2 * n + v - 1; cc = min(max(cc, 0), WW - 1);
            int ccol = (t & 15) * 4;
            if (use_xt) {
                float4 bv = *reinterpret_cast<const float4*>(
                    xT + ((((size_t)b * HH + rr) * WW + cc) * CC) + c0 + ccol);
                Bs[kr][ccol + 0] = bv.x;
                Bs[kr][ccol + 1] = bv.y;
                Bs[kr][ccol + 2] = bv.z;
                Bs[kr][ccol + 3] = bv.w;
            } else {
                #pragma unroll
                for (int j = 0; j < 4; ++j) {
                    int c = c0 + ccol + j;
                    Bs[kr][ccol + j] =
                        x[(((size_t)b * CC + c) * HH + rr) * WW + cc];
                }
            }
        }
        __syncthreads();

        #pragma unroll
        for (int k = 0; k < TILE_K; ++k) {
            float a4[4], b4[4];
            *reinterpret_cast<float4*>(a4) =
                *reinterpret_cast<const float4*>(&As[k][ty * 4]);
            *reinterpret_cast<float4*>(b4) =
                *reinterpret_cast<const float4*>(&Bs[k][tx * 4]);
            #pragma unroll
            for (int i = 0; i < 4; ++i)
                #pragma unroll
                for (int j = 0; j < 4; ++j)
                    acc[i][j] += a4[i] * b4[j];
        }
        __syncthreads();
    }

    const float scale = alpha[0] * 0.25f;
    #pragma unroll
    for (int i = 0; i < 4; ++i) {
        int qr = m0 + ty * 4 + i;
        int Q = qr >> 5, R = qr & 31;
        int h = 2 * Q + u - 1;
        int w = 2 * R + v - 1;
        if (h < 0 || h >= HH || w < 0 || w >= WW) continue;
        #pragma unroll
        for (int j = 0; j < 4; ++j) {
            int c = c0 + tx * 4 + j;
            atomicAdd(&out[(((size_t)b * CC + c) * HH + h) * WW + w],
                      acc[i][j] * scale);
        }
    }
}

// ===========================================================================
extern "C" void kernel_launch(void* const* d_in, const int* in_sizes, int n_in,
                              void* d_out, int out_size, void* d_ws,
                              size_t ws_size, hipStream_t stream) {
    const float* ori_x  = (const float*)d_in[0];
    const float* scores = (const float*)d_in[1];
    const float* alpha  = (const float*)d_in[2];
    float* out = (float*)d_out;

    const size_t need_fast = (TP_ELEMS + BP_ELEMS) * sizeof(_Float16);

    if (ws_size >= need_fast) {
        _Float16* T  = (_Float16*)d_ws;
        _Float16* Bp = T + TP_ELEMS;

        build_T<<<dim3(5, TROWS, 4), 256, 0, stream>>>(scores, T);
        build_B<<<dim3(5, 16, 8), 256, 0, stream>>>(ori_x, Bp);
        gemm_f16<<<dim3(4, 8, 16), 256, 0, stream>>>(T, Bp, ori_x, alpha, out);
    } else {
        float* xT = (float*)d_ws;
        const size_t xt_bytes = (size_t)BB * HH * WW * CC * sizeof(float);
        const int use_xt = (ws_size >= xt_bytes) ? 1 : 0;

        copy_kernel<<<(BB * CC * HH * WW / 4 + 255) / 256, 256, 0, stream>>>(
            ori_x, out, BB * CC * HH * WW / 4);
        if (use_xt)
            transpose_kernel<<<dim3(WW / 32, CC / 32, BB * HH), 256, 0,
                               stream>>>(ori_x, xT);
        pgemm_scatter<<<dim3(NN / TILE_N, QRN / TILE_M, BB), 256, 0, stream>>>(
            scores, xT, ori_x, alpha, out, use_xt);
    }
}

// Round 12
// 55.333 us; speedup vs baseline: 1.1875x; 1.0644x over previous
//
#include <hip/hip_runtime.h>
#include <hip/hip_bf16.h>
#include <hip/hip_fp16.h>

// Problem constants (B=4, C=256, H=W=64, hs=ws=32, rate=2, vk=4, pad=1)
#define BB 4
#define CC 256
#define HH 64
#define WW 64
#define QRN 1024
#define KN  1024
#define NN  4096
#define KDIM 1120            // 33*33 = 1089 padded to 35*32
#define MROWS 1024           // pixels per parity class
#define TROWS 1089           // 33*33 combined-score rows per b

typedef _Float16 f16x8 __attribute__((ext_vector_type(8)));
typedef float f32x4 __attribute__((ext_vector_type(4)));
typedef float f32x16 __attribute__((ext_vector_type(16)));

#define TP_ELEMS ((size_t)BB * TROWS * KDIM)   // 4,878,720 halves (9.76 MB)
#define BP_ELEMS ((size_t)16 * CC * KDIM)      // 4,587,520 halves (9.18 MB)

// ===========================================================================
// FAST PATH
// ===========================================================================

// Merged builder (T part + B part), 1D grid with bijective XCD-chunk
// swizzle so each XCD owns a contiguous qr range of one b -> the 4
// shifted readers of each scores element share one L2 (scores HBM ~1x).
//
// T part:  T[b][qr=Qa*33+Ra][k=(mp,np)] =
//   sum_{dq,dr in {0,1}} [masks] s[b][(Qa-dq)*32+(Ra-dr)][(mp-dq)*32+(np-dr)]
// B part:  Bp[bc][c][k] = x[b][c][clamp(2mp+ua-1)][clamp(2np+va-1)]
//          ua = 1-ph, va = 1-pw, cls = ph*2+pw
//
// Per b: 5445 T blocks (1089 qr x 5 k-chunks) + 160 B blocks (4 cls x
// 8 cgroups x 5 k-chunks) = 5605.  nwg = 4*5605 = 22420.
#define T_BLOCKS 5445
#define PER_B    5605
#define TB_NWG   (BB * PER_B)    // 22420

__global__ __launch_bounds__(256)
void build_TB(const float* __restrict__ s, const float* __restrict__ x,
              _Float16* __restrict__ T, _Float16* __restrict__ Bp) {
    // bijective XCD chunk remap (m204: nwg % 8 != 0 needs the q/r form)
    const int orig = blockIdx.x;
    const int xcd = orig & 7, pos = orig >> 3;
    const int q = TB_NWG / 8, r = TB_NWG % 8;            // 2802, 4
    const int wgid =
        (xcd < r ? xcd * (q + 1) : r * (q + 1) + (xcd - r) * q) + pos;

    const int b = wgid / PER_B;
    const int rem = wgid - b * PER_B;
    const int t = threadIdx.x;

    if (rem < T_BLOCKS) {
        // ---------------- T part ----------------
        const int qr = rem / 5;
        const int kc = rem - qr * 5;
        const int k = kc * 256 + t;
        if (k >= KDIM) return;
        const int Qa = (qr * 993) >> 15;        // qr/33 (exact for qr<2048)
        const int Ra = qr - 33 * Qa;

        const int mp = (k * 993) >> 15;         // k/33 (exact for k<2048)
        const int np = k - 33 * mp;
        const bool q0 = (Qa < 32), q1 = (Qa >= 1);        // block-uniform
        const bool r0 = (Ra < 32), r1 = (Ra >= 1);        // block-uniform
        const bool m0 = (mp < 32), m1 = (mp >= 1) && (mp < 33);
        const bool n0 = (np < 32), n1 = (np >= 1);
        const int col = (mp << 5) + np;
        const float* sb = s + (size_t)b * QRN * KN;

        float v = 0.f;
        if (q0 & r0 & m0 & n0) v += sb[(size_t)((Qa << 5) + Ra) * KN + col];
        if (q0 & r1 & m0 & n1) v += sb[(size_t)((Qa << 5) + Ra - 1) * KN + col - 1];
        if (q1 & r0 & m1 & n0) v += sb[(size_t)(((Qa - 1) << 5) + Ra) * KN + col - 32];
        if (q1 & r1 & m1 & n1) v += sb[(size_t)(((Qa - 1) << 5) + Ra - 1) * KN + col - 33];

        T[((size_t)b * TROWS + qr) * KDIM + k] = (_Float16)v;
    } else {
        // ---------------- B part ----------------
        const int u = rem - T_BLOCKS;           // [0,160)
        const int rest = u / 5;
        const int kc = u - rest * 5;
        const int cls = rest >> 3, cg = rest & 7;
        const int k = kc * 256 + t;
        if (k >= KDIM) return;
        const int ph = cls >> 1, pw = cls & 1;
        const int ua = 1 - ph, va = 1 - pw;
        const int bc = b * 4 + cls;

        const int mp = (k * 993) >> 15;
        const int np = k - 33 * mp;
        int rr = 2 * mp + ua - 1; rr = min(max(rr, 0), HH - 1);
        int cc2 = 2 * np + va - 1; cc2 = min(max(cc2, 0), WW - 1);
        const int off = rr * WW + cc2;

        const float* xb = x + ((size_t)b * CC + cg * 32) * HH * WW;
        _Float16* bpb = Bp + ((size_t)bc * CC + cg * 32) * KDIM + k;

        #pragma unroll 8
        for (int i = 0; i < 32; ++i) {
            bpb[(size_t)i * KDIM] = (_Float16)xb[(size_t)i * HH * WW + off];
        }
    }
}

// GEMM per (b,class): D[c][px] = sum_k Bp[c][k] * T[b][trow(px,cls)][k]
// Tile 64(c) x 128(px), 512 blocks (2/CU). 4 waves = 2(n-half) x 2(k-slice):
// each wave 64m x 64n x K16 per step -> 4 ds_read_b128 per 4 MFMA (1.0 ratio).
// K-step 32, mfma_f32_32x32x16_f16, PF=4 register prefetch ring, double-
// buffered LDS, raw s_barrier + lgkmcnt(0) (prefetch stays in flight),
// s_setprio(1) around the MFMA cluster (T5; 2 independent blocks/CU give
// the CU scheduler role diversity to arbitrate).
// After K-loop: k-slices reduced across wave pairs via LDS, epilogue by the
// ks=0 waves: out = ori_x + 0.25*alpha*D (each output pixel exactly once).
#define A_SLOT 520       // 64*8 + 8 halves
#define B_SLOT 1040      // 128*8 + 8 halves
#define PF 4
#define NT 35            // KDIM/32
__global__ __launch_bounds__(256)
void gemm_f16(const _Float16* __restrict__ T,    // [4][1089][1120] (px side)
              const _Float16* __restrict__ Bp,   // [16][256][1120] (c side)
              const float* __restrict__ orix,
              const float* __restrict__ alphap,
              float* __restrict__ out) {
    __shared__ __align__(16) char smem[32768];   // max(stage 24960, ex 32768)
    _Float16* AmB = (_Float16*)smem;             // [2][4*A_SLOT]
    _Float16* BnB = AmB + 2 * 4 * A_SLOT;        // [2][4*B_SLOT]
    float*    ex  = (float*)smem;                // k-reduction overlay

    // XCD-grouping remap: XCD r gets 64 consecutive wids = 2 bc panels
    // (same b, class pair with complementary pw -> orix/out lines shared).
    const int lin = blockIdx.x + 4 * (blockIdx.y + 8 * blockIdx.z); // 0..511
    const int wid = (lin & 7) * 64 + (lin >> 3);
    const int bc  = wid >> 5;
    const int byy = (wid >> 2) & 7;
    const int bxx = wid & 3;

    const int b = bc >> 2, cls = bc & 3;
    const int ph = cls >> 1, pw = cls & 1;
    const int c0  = bxx * 64;
    const int px0 = byy * 128;

    const int t = threadIdx.x;
    const int wv = t >> 6, l = t & 63;
    const int lr = l & 31;                // row within 32-tile
    const int lh = l >> 5;                // k-half selector
    const int wc = wv & 1;                // n-half (which 64 of 128 px)
    const int ks = wv >> 1;               // k-slice (which 16 of K-step 32)

    const _Float16* Ag = Bp + ((size_t)bc * CC + c0) * KDIM;   // M operand
    const _Float16* Tg = T + (size_t)b * TROWS * KDIM;         // N operand

    // staging: thread covers A row st_row and T rows trow0/trow1
    const int st_row  = t >> 2;           // 0..63
    const int st_slot = t & 3;
    const int pxa = px0 + st_row, pxb = px0 + st_row + 64;
    const int trow0 = ((pxa >> 5) + ph) * 33 + (pxa & 31) + pw;
    const int trow1 = ((pxb >> 5) + ph) * 33 + (pxb & 31) + pw;

    f32x16 acc[2][2];
    #pragma unroll
    for (int i = 0; i < 2; ++i)
        #pragma unroll
        for (int j = 0; j < 2; ++j)
            acc[i][j] = (f32x16)(0.f);

    f16x8 rga[PF], rgb0[PF], rgb1[PF];

    // ---- prologue: issue loads for steps 0..PF-1
    #pragma unroll
    for (int s2 = 0; s2 < PF; ++s2) {
        const size_t kb = s2 * 32 + st_slot * 8;
        rga[s2]  = *reinterpret_cast<const f16x8*>(Ag + (size_t)st_row * KDIM + kb);
        rgb0[s2] = *reinterpret_cast<const f16x8*>(Tg + (size_t)trow0 * KDIM + kb);
        rgb1[s2] = *reinterpret_cast<const f16x8*>(Tg + (size_t)trow1 * KDIM + kb);
    }
    // write step 0 into buf 0
    *reinterpret_cast<f16x8*>(&AmB[st_slot * A_SLOT + st_row * 8]) = rga[0];
    *reinterpret_cast<f16x8*>(&BnB[st_slot * B_SLOT + st_row * 8]) = rgb0[0];
    *reinterpret_cast<f16x8*>(&BnB[st_slot * B_SLOT + (st_row + 64) * 8]) = rgb1[0];
    asm volatile("s_waitcnt lgkmcnt(0)" ::: "memory");
    __builtin_amdgcn_s_barrier();

    #pragma unroll
    for (int ts = 0; ts < NT; ++ts) {
        const int cur = ts & 1;
        // issue prefetch for step ts+PF into the ring slot just freed
        if (ts + PF < NT) {
            const int sl = ts & 3;        // == (ts+PF) & 3
            const size_t kb = (size_t)(ts + PF) * 32 + st_slot * 8;
            rga[sl]  = *reinterpret_cast<const f16x8*>(Ag + (size_t)st_row * KDIM + kb);
            rgb0[sl] = *reinterpret_cast<const f16x8*>(Tg + (size_t)trow0 * KDIM + kb);
            rgb1[sl] = *reinterpret_cast<const f16x8*>(Tg + (size_t)trow1 * KDIM + kb);
        }

        // compute on buf[cur]: this wave's k-slice is slot (ks*2 + lh)
        const int slot = ks * 2 + lh;
        f16x8 af[2], bf[2];
        #pragma unroll
        for (int mt = 0; mt < 2; ++mt)
            af[mt] = *reinterpret_cast<const f16x8*>(
                &AmB[cur * 4 * A_SLOT + slot * A_SLOT + (mt * 32 + lr) * 8]);
        #pragma unroll
        for (int nt2 = 0; nt2 < 2; ++nt2)
            bf[nt2] = *reinterpret_cast<const f16x8*>(
                &BnB[cur * 4 * B_SLOT + slot * B_SLOT +
                     (wc * 64 + nt2 * 32 + lr) * 8]);
        __builtin_amdgcn_s_setprio(1);
        #pragma unroll
        for (int mt = 0; mt < 2; ++mt)
            #pragma unroll
            for (int nt2 = 0; nt2 < 2; ++nt2)
                acc[mt][nt2] = __builtin_amdgcn_mfma_f32_32x32x16_f16(
                    af[mt], bf[nt2], acc[mt][nt2], 0, 0, 0);
        __builtin_amdgcn_s_setprio(0);

        // write step ts+1 into the other buffer (compiler inserts the
        // precise vmcnt for these ring registers; never drains to 0)
        if (ts + 1 < NT) {
            const int ns = (ts + 1) & 3, nb = cur ^ 1;
            *reinterpret_cast<f16x8*>(&AmB[nb * 4 * A_SLOT + st_slot * A_SLOT + st_row * 8]) = rga[ns];
            *reinterpret_cast<f16x8*>(&BnB[nb * 4 * B_SLOT + st_slot * B_SLOT + st_row * 8]) = rgb0[ns];
            *reinterpret_cast<f16x8*>(&BnB[nb * 4 * B_SLOT + st_slot * B_SLOT + (st_row + 64) * 8]) = rgb1[ns];
        }
        asm volatile("s_waitcnt lgkmcnt(0)" ::: "memory");
        __builtin_amdgcn_s_barrier();
    }

    // ---- cross-wave k-slice reduction: ks=1 waves dump, ks=0 waves add.
    // Layout ex[v=mt*2+nt][wc][r][lane]: lanes consecutive -> conflict-free.
    if (ks == 1) {
        #pragma unroll
        for (int mt = 0; mt < 2; ++mt)
            #pragma unroll
            for (int nt2 = 0; nt2 < 2; ++nt2)
                #pragma unroll
                for (int r = 0; r < 16; ++r)
                    ex[((((mt * 2 + nt2) * 2 + wc) * 16) + r) * 64 + l] =
                        acc[mt][nt2][r];
    }
    asm volatile("s_waitcnt lgkmcnt(0)" ::: "memory");
    __builtin_amdgcn_s_barrier();

    if (ks == 0) {
        const float scale = 0.25f * alphap[0];
        #pragma unroll
        for (int mt = 0; mt < 2; ++mt) {
            #pragma unroll
            for (int nt2 = 0; nt2 < 2; ++nt2) {
                #pragma unroll
                for (int r = 0; r < 16; ++r) {
                    float vsum = acc[mt][nt2][r] +
                        ex[((((mt * 2 + nt2) * 2 + wc) * 16) + r) * 64 + l];
                    int c  = c0 + mt * 32 + (r & 3) + 8 * (r >> 2) + 4 * lh;
                    int px = px0 + wc * 64 + nt2 * 32 + lr;
                    int hh = px >> 5, ww2 = px & 31;
                    int h = 2 * hh + ph, wp = 2 * ww2 + pw;
                    size_t idx = (((size_t)b * CC + c) * HH + h) * WW + wp;
                    out[idx] = orix[idx] + scale * vsum;
                }
            }
        }
    }
}

// ===========================================================================
// FALLBACK PATH (round-1 kernels, used only if ws too small)
// ===========================================================================
#define TILE_M 64
#define TILE_N 64
#define TILE_K 16

__global__ void copy_kernel(const float* __restrict__ src,
                            float* __restrict__ dst, int n4) {
    int i = blockIdx.x * blockDim.x + threadIdx.x;
    if (i < n4)
        reinterpret_cast<float4*>(dst)[i] =
            reinterpret_cast<const float4*>(src)[i];
}

__global__ void transpose_kernel(const float* __restrict__ x,
                                 float* __restrict__ xT) {
    __shared__ float tile[32][33];
    int bh = blockIdx.z;
    int b = bh >> 6, h = bh & 63;
    int c0 = blockIdx.y * 32, w0 = blockIdx.x * 32;
    int tw = threadIdx.x & 31;
    int tc = threadIdx.x >> 5;
    #pragma unroll
    for (int i = 0; i < 4; ++i) {
        int c = tc + i * 8;
        tile[c][tw] = x[(((size_t)b * CC + c0 + c) * HH + h) * WW + w0 + tw];
    }
    __syncthreads();
    int tcw = threadIdx.x & 31;
    int twr = threadIdx.x >> 5;
    #pragma unroll
    for (int i = 0; i < 4; ++i) {
        int w = twr + i * 8;
        xT[(((size_t)b * HH + h) * WW + w0 + w) * CC + c0 + tcw] = tile[tcw][w];
    }
}

__global__ __launch_bounds__(256)
void pgemm_scatter(const float* __restrict__ scores,
                   const float* __restrict__ xT,
                   const float* __restrict__ x,
                   const float* __restrict__ alpha,
                   float* __restrict__ out,
                   int use_xt) {
    __shared__ float As[TILE_K][TILE_M];
    __shared__ float Bs[TILE_K][TILE_N];

    const int b      = blockIdx.z;
    const int tile_n = blockIdx.x;
    const int m0     = blockIdx.y * TILE_M;
    const int uv     = tile_n >> 2;
    const int u      = uv >> 2, v = uv & 3;
    const int c0     = (tile_n & 3) * 64;

    const int t  = threadIdx.x;
    const int tx = t & 15;
    const int ty = t >> 4;

    float acc[4][4] = {};
    const float* sb = scores + (size_t)b * QRN * KN;

    for (int k0 = 0; k0 < KN; k0 += TILE_K) {
        {
            int mr = t >> 2;
            int kc = (t & 3) * 4;
            float4 av = *reinterpret_cast<const float4*>(
                sb + (size_t)(m0 + mr) * KN + k0 + kc);
            As[kc + 0][mr] = av.x;
            As[kc + 1][mr] = av.y;
            As[kc + 2][mr] = av.z;
            As[kc + 3][mr] = av.w;
        }
        {
            int kr = t >> 4;
            int kg = k0 + kr;
            int m  = kg >> 5, n = kg & 31;
            int rr = 2 * m + u - 1; rr = min(max(rr, 0), HH - 1);
            int cc = 2 * n + v - 1; cc = min(max(cc, 0), WW - 1);
            int ccol = (t & 15) * 4;
            if (use_xt) {
                float4 bv = *reinterpret_cast<const float4*>(
                    xT + ((((size_t)b * HH + rr) * WW + cc) * CC) + c0 + ccol);
                Bs[kr][ccol + 0] = bv.x;
                Bs[kr][ccol + 1] = bv.y;
                Bs[kr][ccol + 2] = bv.z;
                Bs[kr][ccol + 3] = bv.w;
            } else {
                #pragma unroll
                for (int j = 0; j < 4; ++j) {
                    int c = c0 + ccol + j;
                    Bs[kr][ccol + j] =
                        x[(((size_t)b * CC + c) * HH + rr) * WW + cc];
                }
            }
        }
        __syncthreads();

        #pragma unroll
        for (int k = 0; k < TILE_K; ++k) {
            float a4[4], b4[4];
            *reinterpret_cast<float4*>(a4) =
                *reinterpret_cast<const float4*>(&As[k][ty * 4]);
            *reinterpret_cast<float4*>(b4) =
                *reinterpret_cast<const float4*>(&Bs[k][tx * 4]);
            #pragma unroll
            for (int i = 0; i < 4; ++i)
                #pragma unroll
                for (int j = 0; j < 4; ++j)
                    acc[i][j] += a4[i] * b4[j];
        }
        __syncthreads();
    }

    const float scale = alpha[0] * 0.25f;
    #pragma unroll
    for (int i = 0; i < 4; ++i) {
        int qr = m0 + ty * 4 + i;
        int Q = qr >> 5, R = qr & 31;
        int h = 2 * Q + u - 1;
        int w = 2 * R + v - 1;
        if (h < 0 || h >= HH || w < 0 || w >= WW) continue;
        #pragma unroll
        for (int j = 0; j < 4; ++j) {
            int c = c0 + tx * 4 + j;
            atomicAdd(&out[(((size_t)b * CC + c) * HH + h) * WW + w],
                      acc[i][j] * scale);
        }
    }
}

// ===========================================================================
extern "C" void kernel_launch(void* const* d_in, const int* in_sizes, int n_in,
                              void* d_out, int out_size, void* d_ws,
                              size_t ws_size, hipStream_t stream) {
    const float* ori_x  = (const float*)d_in[0];
    const float* scores = (const float*)d_in[1];
    const float* alpha  = (const float*)d_in[2];
    float* out = (float*)d_out;

    const size_t need_fast = (TP_ELEMS + BP_ELEMS) * sizeof(_Float16);

    if (ws_size >= need_fast) {
        _Float16* T  = (_Float16*)d_ws;
        _Float16* Bp = T + TP_ELEMS;

        build_TB<<<dim3(TB_NWG), 256, 0, stream>>>(scores, ori_x, T, Bp);
        gemm_f16<<<dim3(4, 8, 16), 256, 0, stream>>>(T, Bp, ori_x, alpha, out);
    } else {
        float* xT = (float*)d_ws;
        const size_t xt_bytes = (size_t)BB * HH * WW * CC * sizeof(float);
        const int use_xt = (ws_size >= xt_bytes) ? 1 : 0;

        copy_kernel<<<(BB * CC * HH * WW / 4 + 255) / 256, 256, 0, stream>>>(
            ori_x, out, BB * CC * HH * WW / 4);
        if (use_xt)
            transpose_kernel<<<dim3(WW / 32, CC / 32, BB * HH), 256, 0,
                               stream>>>(ori_x, xT);
        pgemm_scatter<<<dim3(NN / TILE_N, QRN / TILE_M, BB), 256, 0, stream>>>(
            scores, xT, ori_x, alpha, out, use_xt);
    }
}

// Round 13
// 48.985 us; speedup vs baseline: 1.3414x; 1.1296x over previous
//
#include <hip/hip_runtime.h>
#include <hip/hip_bf16.h>
#include <hip/hip_fp16.h>

// Problem constants (B=4, C=256, H=W=64, hs=ws=32, rate=2, vk=4, pad=1)
#define BB 4
#define CC 256
#define HH 64
#define WW 64
#define QRN 1024
#define KN  1024
#define NN  4096
#define KDIM 1120            // 33*33 = 1089 padded to 35*32
#define MROWS 1024           // pixels per parity class
#define TROWS 1089           // 33*33 combined-score rows per b

typedef _Float16 f16x8 __attribute__((ext_vector_type(8)));
typedef float f32x4 __attribute__((ext_vector_type(4)));
typedef float f32x16 __attribute__((ext_vector_type(16)));

#define TP_ELEMS ((size_t)BB * TROWS * KDIM)   // 4,878,720 halves (9.76 MB)
#define BP_ELEMS ((size_t)16 * CC * KDIM)      // 4,587,520 halves (9.18 MB)

// ===========================================================================
// FAST PATH
// ===========================================================================

// Merged builder (T part + B part). One block per (b,qr) for T (threads
// loop all 5 k-chunks: 20 independent loads + 5 stores each — dispatch
// count 22420 -> 4996, 5x the memory-level parallelism per thread).
// Bijective XCD-chunk swizzle keeps the 4 shifted readers of each scores
// element on one XCD's L2.
//
// T part:  T[b][qr=Qa*33+Ra][k=(mp,np)] =
//   sum_{dq,dr in {0,1}} [masks] s[b][(Qa-dq)*32+(Ra-dr)][(mp-dq)*32+(np-dr)]
// B part:  Bp[bc][c][k] = x[b][c][clamp(2mp+ua-1)][clamp(2np+va-1)]
//          ua = 1-ph, va = 1-pw, cls = ph*2+pw
//
// Per b: 1089 T blocks + 160 B blocks (4 cls x 8 cgroups x 5 k-chunks)
// = 1249.  nwg = 4*1249 = 4996.
#define T_BLOCKS 1089
#define PER_B    1249
#define TB_NWG   (BB * PER_B)    // 4996

__global__ __launch_bounds__(256)
void build_TB(const float* __restrict__ s, const float* __restrict__ x,
              _Float16* __restrict__ T, _Float16* __restrict__ Bp) {
    // bijective XCD chunk remap (m204 form; nwg % 8 = 4)
    const int orig = blockIdx.x;
    const int xcd = orig & 7, pos = orig >> 3;
    const int q = TB_NWG / 8, r = TB_NWG % 8;            // 624, 4
    const int wgid =
        (xcd < r ? xcd * (q + 1) : r * (q + 1) + (xcd - r) * q) + pos;

    const int b = wgid / PER_B;
    const int rem = wgid - b * PER_B;
    const int t = threadIdx.x;

    if (rem < T_BLOCKS) {
        // ---------------- T part: one block per (b,qr), all 1120 k ------
        const int qr = rem;
        const int Qa = (qr * 993) >> 15;        // qr/33 (exact for qr<2048)
        const int Ra = qr - 33 * Qa;
        const bool q0 = (Qa < 32), q1 = (Qa >= 1);        // block-uniform
        const bool r0 = (Ra < 32), r1 = (Ra >= 1);        // block-uniform
        const float* sb = s + (size_t)b * QRN * KN;
        // block-uniform row bases (SGPR)
        const float* rb00 = sb + ((size_t)((Qa)     * 32 + (Ra)))     * KN;
        const float* rb01 = sb + ((size_t)((Qa)     * 32 + (Ra - 1))) * KN;
        const float* rb10 = sb + ((size_t)((Qa - 1) * 32 + (Ra)))     * KN;
        const float* rb11 = sb + ((size_t)((Qa - 1) * 32 + (Ra - 1))) * KN;
        _Float16* trow = T + ((size_t)b * TROWS + qr) * KDIM;

        float v[5];
        #pragma unroll
        for (int j = 0; j < 5; ++j) {
            const int k = j * 256 + t;
            v[j] = 0.f;
            if (k < KDIM) {
                const int mp = (k * 993) >> 15;  // k/33 (exact for k<2048)
                const int np = k - 33 * mp;
                const bool m0 = (mp < 32), m1 = (mp >= 1) && (mp < 33);
                const bool n0 = (np < 32), n1 = (np >= 1);
                const int col = (mp << 5) + np;
                if (q0 & r0 & m0 & n0) v[j] += rb00[col];
                if (q0 & r1 & m0 & n1) v[j] += rb01[col - 1];
                if (q1 & r0 & m1 & n0) v[j] += rb10[col - 32];
                if (q1 & r1 & m1 & n1) v[j] += rb11[col - 33];
            }
        }
        #pragma unroll
        for (int j = 0; j < 5; ++j) {
            const int k = j * 256 + t;
            if (k < KDIM) trow[k] = (_Float16)v[j];
        }
    } else {
        // ---------------- B part (shape unchanged from r12) -------------
        const int u = rem - T_BLOCKS;           // [0,160)
        const int rest = u / 5;
        const int kc = u - rest * 5;
        const int cls = rest >> 3, cg = rest & 7;
        const int k = kc * 256 + t;
        if (k >= KDIM) return;
        const int ph = cls >> 1, pw = cls & 1;
        const int ua = 1 - ph, va = 1 - pw;
        const int bc = b * 4 + cls;

        const int mp = (k * 993) >> 15;
        const int np = k - 33 * mp;
        int rr = 2 * mp + ua - 1; rr = min(max(rr, 0), HH - 1);
        int cc2 = 2 * np + va - 1; cc2 = min(max(cc2, 0), WW - 1);
        const int off = rr * WW + cc2;

        const float* xb = x + ((size_t)b * CC + cg * 32) * HH * WW;
        _Float16* bpb = Bp + ((size_t)bc * CC + cg * 32) * KDIM + k;

        #pragma unroll 8
        for (int i = 0; i < 32; ++i) {
            bpb[(size_t)i * KDIM] = (_Float16)xb[(size_t)i * HH * WW + off];
        }
    }
}

// GEMM per (b,class): D[c][px] = sum_k Bp[c][k] * T[b][trow(px,cls)][k]
// Tile 64(c) x 128(px), 512 blocks (2/CU). 4 waves = 2(n-half) x 2(k-slice):
// each wave 64m x 64n x K16 per step -> 4 ds_read_b128 per 4 MFMA (1.0 ratio).
// K-step 32, mfma_f32_32x32x16_f16, PF=4 register prefetch ring, double-
// buffered LDS, raw s_barrier + lgkmcnt(0) (prefetch stays in flight),
// s_setprio(1) around the MFMA cluster (T5).
// After K-loop: k-slices reduced across wave pairs via LDS, epilogue by the
// ks=0 waves: out = ori_x + 0.25*alpha*D (each output pixel exactly once).
#define A_SLOT 520       // 64*8 + 8 halves
#define B_SLOT 1040      // 128*8 + 8 halves
#define PF 4
#define NT 35            // KDIM/32
__global__ __launch_bounds__(256)
void gemm_f16(const _Float16* __restrict__ T,    // [4][1089][1120] (px side)
              const _Float16* __restrict__ Bp,   // [16][256][1120] (c side)
              const float* __restrict__ orix,
              const float* __restrict__ alphap,
              float* __restrict__ out) {
    __shared__ __align__(16) char smem[32768];   // max(stage 24960, ex 32768)
    _Float16* AmB = (_Float16*)smem;             // [2][4*A_SLOT]
    _Float16* BnB = AmB + 2 * 4 * A_SLOT;        // [2][4*B_SLOT]
    float*    ex  = (float*)smem;                // k-reduction overlay

    // XCD-grouping remap: XCD r gets 64 consecutive wids = 2 bc panels
    const int lin = blockIdx.x + 4 * (blockIdx.y + 8 * blockIdx.z); // 0..511
    const int wid = (lin & 7) * 64 + (lin >> 3);
    const int bc  = wid >> 5;
    const int byy = (wid >> 2) & 7;
    const int bxx = wid & 3;

    const int b = bc >> 2, cls = bc & 3;
    const int ph = cls >> 1, pw = cls & 1;
    const int c0  = bxx * 64;
    const int px0 = byy * 128;

    const int t = threadIdx.x;
    const int wv = t >> 6, l = t & 63;
    const int lr = l & 31;                // row within 32-tile
    const int lh = l >> 5;                // k-half selector
    const int wc = wv & 1;                // n-half (which 64 of 128 px)
    const int ks = wv >> 1;               // k-slice (which 16 of K-step 32)

    const _Float16* Ag = Bp + ((size_t)bc * CC + c0) * KDIM;   // M operand
    const _Float16* Tg = T + (size_t)b * TROWS * KDIM;         // N operand

    // staging: thread covers A row st_row and T rows trow0/trow1
    const int st_row  = t >> 2;           // 0..63
    const int st_slot = t & 3;
    const int pxa = px0 + st_row, pxb = px0 + st_row + 64;
    const int trow0 = ((pxa >> 5) + ph) * 33 + (pxa & 31) + pw;
    const int trow1 = ((pxb >> 5) + ph) * 33 + (pxb & 31) + pw;

    f32x16 acc[2][2];
    #pragma unroll
    for (int i = 0; i < 2; ++i)
        #pragma unroll
        for (int j = 0; j < 2; ++j)
            acc[i][j] = (f32x16)(0.f);

    f16x8 rga[PF], rgb0[PF], rgb1[PF];

    // ---- prologue: issue loads for steps 0..PF-1
    #pragma unroll
    for (int s2 = 0; s2 < PF; ++s2) {
        const size_t kb = s2 * 32 + st_slot * 8;
        rga[s2]  = *reinterpret_cast<const f16x8*>(Ag + (size_t)st_row * KDIM + kb);
        rgb0[s2] = *reinterpret_cast<const f16x8*>(Tg + (size_t)trow0 * KDIM + kb);
        rgb1[s2] = *reinterpret_cast<const f16x8*>(Tg + (size_t)trow1 * KDIM + kb);
    }
    // write step 0 into buf 0
    *reinterpret_cast<f16x8*>(&AmB[st_slot * A_SLOT + st_row * 8]) = rga[0];
    *reinterpret_cast<f16x8*>(&BnB[st_slot * B_SLOT + st_row * 8]) = rgb0[0];
    *reinterpret_cast<f16x8*>(&BnB[st_slot * B_SLOT + (st_row + 64) * 8]) = rgb1[0];
    asm volatile("s_waitcnt lgkmcnt(0)" ::: "memory");
    __builtin_amdgcn_s_barrier();

    #pragma unroll
    for (int ts = 0; ts < NT; ++ts) {
        const int cur = ts & 1;
        // issue prefetch for step ts+PF into the ring slot just freed
        if (ts + PF < NT) {
            const int sl = ts & 3;        // == (ts+PF) & 3
            const size_t kb = (size_t)(ts + PF) * 32 + st_slot * 8;
            rga[sl]  = *reinterpret_cast<const f16x8*>(Ag + (size_t)st_row * KDIM + kb);
            rgb0[sl] = *reinterpret_cast<const f16x8*>(Tg + (size_t)trow0 * KDIM + kb);
            rgb1[sl] = *reinterpret_cast<const f16x8*>(Tg + (size_t)trow1 * KDIM + kb);
        }

        // compute on buf[cur]: this wave's k-slice is slot (ks*2 + lh)
        const int slot = ks * 2 + lh;
        f16x8 af[2], bf[2];
        #pragma unroll
        for (int mt = 0; mt < 2; ++mt)
            af[mt] = *reinterpret_cast<const f16x8*>(
                &AmB[cur * 4 * A_SLOT + slot * A_SLOT + (mt * 32 + lr) * 8]);
        #pragma unroll
        for (int nt2 = 0; nt2 < 2; ++nt2)
            bf[nt2] = *reinterpret_cast<const f16x8*>(
                &BnB[cur * 4 * B_SLOT + slot * B_SLOT +
                     (wc * 64 + nt2 * 32 + lr) * 8]);
        __builtin_amdgcn_s_setprio(1);
        #pragma unroll
        for (int mt = 0; mt < 2; ++mt)
            #pragma unroll
            for (int nt2 = 0; nt2 < 2; ++nt2)
                acc[mt][nt2] = __builtin_amdgcn_mfma_f32_32x32x16_f16(
                    af[mt], bf[nt2], acc[mt][nt2], 0, 0, 0);
        __builtin_amdgcn_s_setprio(0);

        // write step ts+1 into the other buffer (compiler inserts the
        // precise vmcnt for these ring registers; never drains to 0)
        if (ts + 1 < NT) {
            const int ns = (ts + 1) & 3, nb = cur ^ 1;
            *reinterpret_cast<f16x8*>(&AmB[nb * 4 * A_SLOT + st_slot * A_SLOT + st_row * 8]) = rga[ns];
            *reinterpret_cast<f16x8*>(&BnB[nb * 4 * B_SLOT + st_slot * B_SLOT + st_row * 8]) = rgb0[ns];
            *reinterpret_cast<f16x8*>(&BnB[nb * 4 * B_SLOT + st_slot * B_SLOT + (st_row + 64) * 8]) = rgb1[ns];
        }
        asm volatile("s_waitcnt lgkmcnt(0)" ::: "memory");
        __builtin_amdgcn_s_barrier();
    }

    // ---- cross-wave k-slice reduction: ks=1 waves dump, ks=0 waves add.
    if (ks == 1) {
        #pragma unroll
        for (int mt = 0; mt < 2; ++mt)
            #pragma unroll
            for (int nt2 = 0; nt2 < 2; ++nt2)
                #pragma unroll
                for (int r = 0; r < 16; ++r)
                    ex[((((mt * 2 + nt2) * 2 + wc) * 16) + r) * 64 + l] =
                        acc[mt][nt2][r];
    }
    asm volatile("s_waitcnt lgkmcnt(0)" ::: "memory");
    __builtin_amdgcn_s_barrier();

    if (ks == 0) {
        const float scale = 0.25f * alphap[0];
        #pragma unroll
        for (int mt = 0; mt < 2; ++mt) {
            #pragma unroll
            for (int nt2 = 0; nt2 < 2; ++nt2) {
                #pragma unroll
                for (int r = 0; r < 16; ++r) {
                    float vsum = acc[mt][nt2][r] +
                        ex[((((mt * 2 + nt2) * 2 + wc) * 16) + r) * 64 + l];
                    int c  = c0 + mt * 32 + (r & 3) + 8 * (r >> 2) + 4 * lh;
                    int px = px0 + wc * 64 + nt2 * 32 + lr;
                    int hh = px >> 5, ww2 = px & 31;
                    int h = 2 * hh + ph, wp = 2 * ww2 + pw;
                    size_t idx = (((size_t)b * CC + c) * HH + h) * WW + wp;
                    out[idx] = orix[idx] + scale * vsum;
                }
            }
        }
    }
}

// ===========================================================================
// FALLBACK PATH (round-1 kernels, used only if ws too small)
// ===========================================================================
#define TILE_M 64
#define TILE_N 64
#define TILE_K 16

__global__ void copy_kernel(const float* __restrict__ src,
                            float* __restrict__ dst, int n4) {
    int i = blockIdx.x * blockDim.x + threadIdx.x;
    if (i < n4)
        reinterpret_cast<float4*>(dst)[i] =
            reinterpret_cast<const float4*>(src)[i];
}

__global__ void transpose_kernel(const float* __restrict__ x,
                                 float* __restrict__ xT) {
    __shared__ float tile[32][33];
    int bh = blockIdx.z;
    int b = bh >> 6, h = bh & 63;
    int c0 = blockIdx.y * 32, w0 = blockIdx.x * 32;
    int tw = threadIdx.x & 31;
    int tc = threadIdx.x >> 5;
    #pragma unroll
    for (int i = 0; i < 4; ++i) {
        int c = tc + i * 8;
        tile[c][tw] = x[(((size_t)b * CC + c0 + c) * HH + h) * WW + w0 + tw];
    }
    __syncthreads();
    int tcw = threadIdx.x & 31;
    int twr = threadIdx.x >> 5;
    #pragma unroll
    for (int i = 0; i < 4; ++i) {
        int w = twr + i * 8;
        xT[(((size_t)b * HH + h) * WW + w0 + w) * CC + c0 + tcw] = tile[tcw][w];
    }
}

__global__ __launch_bounds__(256)
void pgemm_scatter(const float* __restrict__ scores,
                   const float* __restrict__ xT,
                   const float* __restrict__ x,
                   const float* __restrict__ alpha,
                   float* __restrict__ out,
                   int use_xt) {
    __shared__ float As[TILE_K][TILE_M];
    __shared__ float Bs[TILE_K][TILE_N];

    const int b      = blockIdx.z;
    const int tile_n = blockIdx.x;
    const int m0     = blockIdx.y * TILE_M;
    const int uv     = tile_n >> 2;
    const int u      = uv >> 2, v = uv & 3;
    const int c0     = (tile_n & 3) * 64;

    const int t  = threadIdx.x;
    const int tx = t & 15;
    const int ty = t >> 4;

    float acc[4][4] = {};
    const float* sb = scores + (size_t)b * QRN * KN;

    for (int k0 = 0; k0 < KN; k0 += TILE_K) {
        {
            int mr = t >> 2;
            int kc = (t & 3) * 4;
            float4 av = *reinterpret_cast<const float4*>(
                sb + (size_t)(m0 + mr) * KN + k0 + kc);
            As[kc + 0][mr] = av.x;
            As[kc + 1][mr] = av.y;
            As[kc + 2][mr] = av.z;
            As[kc + 3][mr] = av.w;
        }
        {
            int kr = t >> 4;
            int kg = k0 + kr;
            int m  = kg >> 5, n = kg & 31;
            int rr = 2 * m + u - 1; rr = min(max(rr, 0), HH - 1);
            int cc = 2 * n + v - 1; cc = min(max(cc, 0), WW - 1);
            int ccol = (t & 15) * 4;
            if (use_xt) {
                float4 bv = *reinterpret_cast<const float4*>(
                    xT + ((((size_t)b * HH + rr) * WW + cc) * CC) + c0 + ccol);
                Bs[kr][ccol + 0] = bv.x;
                Bs[kr][ccol + 1] = bv.y;
                Bs[kr][ccol + 2] = bv.z;
                Bs[kr][ccol + 3] = bv.w;
            } else {
                #pragma unroll
                for (int j = 0; j < 4; ++j) {
                    int c = c0 + ccol + j;
                    Bs[kr][ccol + j] =
                        x[(((size_t)b * CC + c) * HH + rr) * WW + cc];
                }
            }
        }
        __syncthreads();

        #pragma unroll
        for (int k = 0; k < TILE_K; ++k) {
            float a4[4], b4[4];
            *reinterpret_cast<float4*>(a4) =
                *reinterpret_cast<const float4*>(&As[k][ty * 4]);
            *reinterpret_cast<float4*>(b4) =
                *reinterpret_cast<const float4*>(&Bs[k][tx * 4]);
            #pragma unroll
            for (int i = 0; i < 4; ++i)
                #pragma unroll
                for (int j = 0; j < 4; ++j)
                    acc[i][j] += a4[i] * b4[j];
        }
        __syncthreads();
    }

    const float scale = alpha[0] * 0.25f;
    #pragma unroll
    for (int i = 0; i < 4; ++i) {
        int qr = m0 + ty * 4 + i;
        int Q = qr >> 5, R = qr & 31;
        int h = 2 * Q + u - 1;
        int w = 2 * R + v - 1;
        if (h < 0 || h >= HH || w < 0 || w >= WW) continue;
        #pragma unroll
        for (int j = 0; j < 4; ++j) {
            int c = c0 + tx * 4 + j;
            atomicAdd(&out[(((size_t)b * CC + c) * HH + h) * WW + w],
                      acc[i][j] * scale);
        }
    }
}

// ===========================================================================
extern "C" void kernel_launch(void* const* d_in, const int* in_sizes, int n_in,
                              void* d_out, int out_size, void* d_ws,
                              size_t ws_size, hipStream_t stream) {
    const float* ori_x  = (const float*)d_in[0];
    const float* scores = (const float*)d_in[1];
    const float* alpha  = (const float*)d_in[2];
    float* out = (float*)d_out;

    const size_t need_fast = (TP_ELEMS + BP_ELEMS) * sizeof(_Float16);

    if (ws_size >= need_fast) {
        _Float16* T  = (_Float16*)d_ws;
        _Float16* Bp = T + TP_ELEMS;

        build_TB<<<dim3(TB_NWG), 256, 0, stream>>>(scores, ori_x, T, Bp);
        gemm_f16<<<dim3(4, 8, 16), 256, 0, stream>>>(T, Bp, ori_x, alpha, out);
    } else {
        float* xT = (float*)d_ws;
        const size_t xt_bytes = (size_t)BB * HH * WW * CC * sizeof(float);
        const int use_xt = (ws_size >= xt_bytes) ? 1 : 0;

        copy_kernel<<<(BB * CC * HH * WW / 4 + 255) / 256, 256, 0, stream>>>(
            ori_x, out, BB * CC * HH * WW / 4);
        if (use_xt)
            transpose_kernel<<<dim3(WW / 32, CC / 32, BB * HH), 256, 0,
                               stream>>>(ori_x, xT);
        pgemm_scatter<<<dim3(NN / TILE_N, QRN / TILE_M, BB), 256, 0, stream>>>(
            scores, xT, ori_x, alpha, out, use_xt);
    }
}